// Round 15
// baseline (1254.530 us; speedup 1.0000x reference)
//
#include <hip/hip_runtime.h>
#include <hip/hip_bf16.h>
#include <hip/hip_fp16.h>
#include <math.h>

constexpr int B = 32, S = 64, T = 64, H = 512, V = 32000;
constexpr int G3 = 3 * H;     // 1536
constexpr int BT = B * T;     // 2048

// ---- workspace layout (float slots) ----
constexpr size_t UAK_OFF    = 0;          // f32 [B*S][512]      1,048,576
constexpr size_t GIE_OFF    = 1048576;    // f32 [B*T][1536]     -> 4,194,304
constexpr size_t KWTH_OFF   = 4194304;    // f16 [B][G3][64]     -> 5,767,168
constexpr size_t WA2T_OFF   = 5767168;    // u32 [256][512]      -> 5,898,240
constexpr size_t WHH2T_OFF  = 5898240;    // u32 [256][1536]     -> 6,291,456
constexpr size_t QP_OFF     = 6291456;    // f32 [2][B][8][512]  262,144 -> 6,553,600
constexpr size_t FLG_OFF    = 7340032;    // int [T][B][8] = 16,384 -> 7,356,416
constexpr size_t OWBF_OFF   = 0;          // bf16 [V*H] = 8,192,000 slots; aliases all
                                          // of the above (dead after k_recur)
constexpr size_t HALL_OFF   = 8192000;    // f32 [(T+1)*B*H]     -> 9,256,960
constexpr size_t STATS_OFF  = 8192000;    // f32 [2048][512]; reuses HALL (dead after recur)
constexpr size_t HBF_OFF    = 9256960;    // bf16 [B*T*H] -> 9,781,248
// f16 staging for precompute MFMA (dead after precompute)
constexpr size_t KEYSH_OFF  = 10000000;   // f16 [2048][512] -> 10,524,288
constexpr size_t GEH_OFF    = 10524288;   // f16 [2048][512] -> 11,048,576
constexpr size_t UAWH_OFF   = 11048576;   // f16 [512][512]  -> 11,179,648
constexpr size_t WLOH_OFF   = 11179648;   // f16 [1536][512] -> 11,572,864
constexpr size_t WCTXH_OFF  = 11572864;   // f16 [1536][512] -> 11,966,080

typedef __attribute__((ext_vector_type(8))) short bf16x8;
typedef __attribute__((ext_vector_type(4))) float f32x4;
typedef __attribute__((ext_vector_type(4))) int i32x4;
typedef _Float16 f16x8 __attribute__((ext_vector_type(8)));
typedef _Float16 h2v __attribute__((ext_vector_type(2)));

__device__ __forceinline__ float fast_tanh(float x) {
  float ax = fabsf(x);
  float e = __expf(-2.f * ax);
  float r = (1.f - e) / (1.f + e);
  return x < 0.f ? -r : r;
}
__device__ __forceinline__ float fast_sig(float x) {
  return 1.f / (1.f + __expf(-x));
}
__device__ __forceinline__ unsigned pack_h2(float a, float b) {
  __half2 h = __floats2half2_rn(a, b);
  return *(unsigned*)&h;
}
__device__ __forceinline__ ushort f2h(float v) {
  __half h = __float2half(v);
  return *(ushort*)&h;
}
__device__ __forceinline__ float dot2acc(unsigned w, unsigned h, float c) {
  return __builtin_amdgcn_fdot2(__builtin_bit_cast(h2v, w),
                                __builtin_bit_cast(h2v, h), c, false);
}
// coherent (LLC) 8-flag poll, one vmcnt
__device__ __forceinline__ int poll8(const int* p) {
  i32x4 a, b;
  asm volatile("global_load_dwordx4 %0, %2, off sc0 sc1\n\t"
               "global_load_dwordx4 %1, %3, off sc0 sc1\n\t"
               "s_waitcnt vmcnt(0)"
               : "=v"(a), "=v"(b) : "v"(p), "v"(p + 4) : "memory");
  return a.x & a.y & a.z & a.w & b.x & b.y & b.z & b.w;
}
__device__ __forceinline__ void store_coh_i32(int* p, int v) {
  asm volatile("global_store_dword %0, %1, off sc0 sc1" :: "v"(p), "v"(v) : "memory");
}
__device__ __forceinline__ void store_coh_f32(float* p, float v) {
  asm volatile("global_store_dword %0, %1, off sc0 sc1" :: "v"(p), "v"(v) : "memory");
}
__device__ __forceinline__ float load_coh_f32(const float* p) {
  float v;
  asm volatile("global_load_dword %0, %1, off sc0 sc1" : "=v"(v) : "v"(p) : "memory");
  return v;
}

// -------------------- consolidated prep: init + f16 convs + k-major packs --------------------
__global__ void k_prep(const float* __restrict__ eh, const int* __restrict__ tgt,
                       const float* __restrict__ keys, const float* __restrict__ emb,
                       const float* __restrict__ Ua_w, const float* __restrict__ W_ih,
                       const float* __restrict__ Wa_w, const float* __restrict__ W_hh,
                       float* __restrict__ ws) {
  int blk = blockIdx.x, tid = threadIdx.x;
  if (blk < 256) {
    int i = blk * 256 + tid;
    if (i < T * B * 8) ((int*)(ws + FLG_OFF))[i] = 0;
    if (i < B * H) ws[HALL_OFF + i] = eh[i];
    return;
  }
  if (blk < 1280) {  // keys -> KEYSH f16
    int i4 = ((blk - 256) * 256 + tid) * 4;
    float4 v = *(const float4*)&keys[i4];
    ushort4 o; o.x = f2h(v.x); o.y = f2h(v.y); o.z = f2h(v.z); o.w = f2h(v.w);
    *(ushort4*)&((ushort*)(ws + KEYSH_OFF))[i4] = o;
    return;
  }
  if (blk < 2304) {  // emb[token(row)] -> GEH f16
    int i4 = ((blk - 1280) * 256 + tid) * 4;
    int row = i4 >> 9, k = i4 & 511;
    int tok = (row & 63) ? tgt[row - 1] : 0;
    float4 v = *(const float4*)&emb[(size_t)tok * 512 + k];
    ushort4 o; o.x = f2h(v.x); o.y = f2h(v.y); o.z = f2h(v.z); o.w = f2h(v.w);
    *(ushort4*)&((ushort*)(ws + GEH_OFF))[i4] = o;
    return;
  }
  if (blk < 2560) {  // Ua_w -> UAWH
    int i4 = ((blk - 2304) * 256 + tid) * 4;
    float4 v = *(const float4*)&Ua_w[i4];
    ushort4 o; o.x = f2h(v.x); o.y = f2h(v.y); o.z = f2h(v.z); o.w = f2h(v.w);
    *(ushort4*)&((ushort*)(ws + UAWH_OFF))[i4] = o;
    return;
  }
  if (blk < 3328) {  // W_ih[:, 0:512] -> WLOH
    int i4 = ((blk - 2560) * 256 + tid) * 4;
    int row = i4 >> 9, k = i4 & 511;
    float4 v = *(const float4*)&W_ih[(size_t)row * 1024 + k];
    ushort4 o; o.x = f2h(v.x); o.y = f2h(v.y); o.z = f2h(v.z); o.w = f2h(v.w);
    *(ushort4*)&((ushort*)(ws + WLOH_OFF))[i4] = o;
    return;
  }
  if (blk < 4096) {  // W_ih[:, 512:1024] -> WCTXH
    int i4 = ((blk - 3328) * 256 + tid) * 4;
    int row = i4 >> 9, k = i4 & 511;
    float4 v = *(const float4*)&W_ih[(size_t)row * 1024 + 512 + k];
    ushort4 o; o.x = f2h(v.x); o.y = f2h(v.y); o.z = f2h(v.z); o.w = f2h(v.w);
    *(ushort4*)&((ushort*)(ws + WCTXH_OFF))[i4] = o;
    return;
  }
  if (blk < 4608) {  // pack Wa k-major [256][512]
    int i = (blk - 4096) * 256 + tid;
    int r = i >> 8, kk = i & 255;
    float2 v = *(const float2*)&Wa_w[(size_t)r * 512 + 2 * kk];
    ((unsigned*)(ws + WA2T_OFF))[(size_t)kk * 512 + r] = pack_h2(v.x, v.y);
    return;
  }
  {                  // pack Whh k-major [256][1536]
    int i = (blk - 4608) * 256 + tid;
    int r = i >> 8, kk = i & 255;
    float2 v = *(const float2*)&W_hh[(size_t)r * 512 + 2 * kk];
    ((unsigned*)(ws + WHH2T_OFF))[(size_t)kk * 1536 + r] = pack_h2(v.x, v.y);
  }
}

// -------------------- out_w fp32 -> bf16 (runs AFTER recurrence; aliases ws) ----
__global__ void k_conv_outw(const float* __restrict__ w, ushort* __restrict__ o, int n4) {
  int i = blockIdx.x * blockDim.x + threadIdx.x;
  if (i < n4) {
    float4 v = *(const float4*)&w[(size_t)i * 4];
    ushort4 u;
    __hip_bfloat16 h0 = __float2bfloat16(v.x); u.x = *(ushort*)&h0;
    __hip_bfloat16 h1 = __float2bfloat16(v.y); u.y = *(ushort*)&h1;
    __hip_bfloat16 h2 = __float2bfloat16(v.z); u.z = *(ushort*)&h2;
    __hip_bfloat16 h3 = __float2bfloat16(v.w); u.w = *(ushort*)&h3;
    *(ushort4*)&o[(size_t)i * 4] = u;
  }
}

// -------- f16 MFMA GEMM 128x128 tiles: C[m*ldc+n] = Ah[m,:].Bh[n,:] + bias[n] --------
__global__ __launch_bounds__(256) void k_mfma128(
    const ushort* __restrict__ Ah, const ushort* __restrict__ Bh,
    const float* __restrict__ bias, float* __restrict__ C, int ldc) {
  __shared__ __align__(16) ushort As[128 * 32];
  __shared__ __align__(16) ushort Bs[128 * 32];
  int bm = blockIdx.y, bn = blockIdx.x;
  int tid = threadIdx.x;
  int lane = tid & 63, wv = tid >> 6;
  int wm = wv >> 1, wn = wv & 1;
  int kc = lane >> 4, rl = lane & 15;
  f32x4 acc[4][4] = {};
  int c0 = wv * 128 + lane, c1 = c0 + 64;
  const ushort* ga0 = Ah + (size_t)(bm * 128 + (c0 >> 2)) * 512 + (c0 & 3) * 8;
  const ushort* ga1 = Ah + (size_t)(bm * 128 + (c1 >> 2)) * 512 + (c1 & 3) * 8;
  const ushort* gb0 = Bh + (size_t)(bn * 128 + (c0 >> 2)) * 512 + (c0 & 3) * 8;
  const ushort* gb1 = Bh + (size_t)(bn * 128 + (c1 >> 2)) * 512 + (c1 & 3) * 8;
  for (int k0 = 0; k0 < 512; k0 += 32) {
    __syncthreads();
    __builtin_amdgcn_global_load_lds(
        (const __attribute__((address_space(1))) void*)(ga0 + k0),
        (__attribute__((address_space(3))) void*)((char*)As + wv * 2048), 16, 0, 0);
    __builtin_amdgcn_global_load_lds(
        (const __attribute__((address_space(1))) void*)(ga1 + k0),
        (__attribute__((address_space(3))) void*)((char*)As + wv * 2048 + 1024), 16, 0, 0);
    __builtin_amdgcn_global_load_lds(
        (const __attribute__((address_space(1))) void*)(gb0 + k0),
        (__attribute__((address_space(3))) void*)((char*)Bs + wv * 2048), 16, 0, 0);
    __builtin_amdgcn_global_load_lds(
        (const __attribute__((address_space(1))) void*)(gb1 + k0),
        (__attribute__((address_space(3))) void*)((char*)Bs + wv * 2048 + 1024), 16, 0, 0);
    __syncthreads();
    f16x8 af[4], bfv[4];
#pragma unroll
    for (int f = 0; f < 4; f++) {
      af[f] = *(const f16x8*)&As[(wm * 64 + f * 16 + rl) * 32 + kc * 8];
      bfv[f] = *(const f16x8*)&Bs[(wn * 64 + f * 16 + rl) * 32 + kc * 8];
    }
#pragma unroll
    for (int i = 0; i < 4; i++)
#pragma unroll
      for (int j = 0; j < 4; j++)
        acc[i][j] = __builtin_amdgcn_mfma_f32_16x16x32_f16(af[i], bfv[j], acc[i][j], 0, 0, 0);
  }
  int cl = lane & 15, rg = lane >> 4;
#pragma unroll
  for (int i = 0; i < 4; i++) {
    int m = bm * 128 + wm * 64 + i * 16 + rg * 4;
#pragma unroll
    for (int j = 0; j < 4; j++) {
      int n = bn * 128 + wn * 64 + j * 16 + cl;
      float bv = bias[n];
#pragma unroll
      for (int r = 0; r < 4; r++)
        C[(size_t)(m + r) * ldc + n] = acc[i][j][r] + bv;
    }
  }
}

// -------- f16 MFMA KWT: per b, [1536 x 64] = Wctx[1536,512] . keys_b[64,512]^T -> f16 --------
__global__ __launch_bounds__(256) void k_mfma_kwt(
    const ushort* __restrict__ Wctxh, const ushort* __restrict__ keysh,
    ushort* __restrict__ KWTh) {
  __shared__ __align__(16) ushort As[128 * 32];
  __shared__ __align__(16) ushort Bs[64 * 32];
  int bm = blockIdx.x, b = blockIdx.y;
  int tid = threadIdx.x;
  int lane = tid & 63, wv = tid >> 6;
  int kc = lane >> 4, rl = lane & 15;
  f32x4 acc[2][4] = {};
  int c0 = tid, c2 = tid + 256;
  const ushort* ga0 = Wctxh + (size_t)(bm * 128 + (c0 >> 2)) * 512 + (c0 & 3) * 8;
  const ushort* ga1 = Wctxh + (size_t)(bm * 128 + (c2 >> 2)) * 512 + (c2 & 3) * 8;
  const ushort* gb0 = keysh + (size_t)(b * 64 + (c0 >> 2)) * 512 + (c0 & 3) * 8;
  for (int k0 = 0; k0 < 512; k0 += 32) {
    __syncthreads();
    __builtin_amdgcn_global_load_lds(
        (const __attribute__((address_space(1))) void*)(ga0 + k0),
        (__attribute__((address_space(3))) void*)((char*)As + wv * 1024), 16, 0, 0);
    __builtin_amdgcn_global_load_lds(
        (const __attribute__((address_space(1))) void*)(ga1 + k0),
        (__attribute__((address_space(3))) void*)((char*)As + 4096 + wv * 1024), 16, 0, 0);
    __builtin_amdgcn_global_load_lds(
        (const __attribute__((address_space(1))) void*)(gb0 + k0),
        (__attribute__((address_space(3))) void*)((char*)Bs + wv * 1024), 16, 0, 0);
    __syncthreads();
    f16x8 af[2], bfv[4];
#pragma unroll
    for (int f = 0; f < 2; f++)
      af[f] = *(const f16x8*)&As[(wv * 32 + f * 16 + rl) * 32 + kc * 8];
#pragma unroll
    for (int j = 0; j < 4; j++)
      bfv[j] = *(const f16x8*)&Bs[(j * 16 + rl) * 32 + kc * 8];
#pragma unroll
    for (int i = 0; i < 2; i++)
#pragma unroll
      for (int j = 0; j < 4; j++)
        acc[i][j] = __builtin_amdgcn_mfma_f32_16x16x32_f16(af[i], bfv[j], acc[i][j], 0, 0, 0);
  }
  int cl = lane & 15, rg = lane >> 4;
#pragma unroll
  for (int i = 0; i < 2; i++) {
    int m = bm * 128 + wv * 32 + i * 16 + rg * 4;
#pragma unroll
    for (int j = 0; j < 4; j++) {
      int n = j * 16 + cl;
#pragma unroll
      for (int r = 0; r < 4; r++)
        KWTh[((size_t)b * G3 + m + r) * 64 + n] = f2h(acc[i][j][r]);
    }
  }
}

// -------------------- persistent recurrence: ONE exchange per step --------------------
// WG w: b = w&31, cb = w>>5. Per step each WG publishes {h-slice, qp-slice =
// Wa[:,kslice].h_slice} under ONE flag. Consumers sum 8 qp -> full q, compute ALL
// 64 scores locally (f16 UAK in LDS, stride 261 -> 2-way conflict-free), local
// softmax (no 2nd exchange), gh from global k-major Whh, gic from f16 KWT in LDS.
// QP parity-2 safe: flag[t]=1 implies that peer COMPLETED step t-1 incl. its
// qp(t-1) reads; a WG writes qp(t+1) (same slot as qp(t-1)) only after polling
// all flag[t]. Max lead across a batch group = 1 step.
__global__ __launch_bounds__(256) void k_recur(
    const float* __restrict__ Wa_b, const float* __restrict__ Va_w,
    const float* __restrict__ Va_b, const float* __restrict__ b_hh,
    const unsigned* __restrict__ WA2T, const unsigned* __restrict__ WHH2T,
    float* __restrict__ ws, float* __restrict__ attn_out, float* __restrict__ ht_out) {
  const int w = blockIdx.x;
  const int tid = threadIdx.x;
  const int b = w & 31, cb = w >> 5;
  const int j0 = cb * 64;
  int* flg = (int*)(ws + FLG_OFF);
  __hip_bfloat16* HBF = (__hip_bfloat16*)(ws + HBF_OFF);
  const float* GIE = ws + GIE_OFF;
  float* QP = ws + QP_OFF;
  const unsigned* KWT32 = (const unsigned*)(ws + KWTH_OFF);

  __shared__ unsigned sUA[64][261];   // f16 UAK pairs, 66.8 KB, stride%32==5
  __shared__ unsigned sKW[192][37];   // f16 KWT pairs, 28.4 KB, stride%32==5
  __shared__ unsigned sH2[256];
  __shared__ unsigned sHn2[32];
  __shared__ float sq[512];
  __shared__ float sVa[512], sWab[512];
  __shared__ float spp[64][5];
  __shared__ float swt[64];
  __shared__ unsigned sW2[32];
  __shared__ float sga[4][64];
  __shared__ float shn[64];
  __shared__ float sBhh[192];

  // ---- one-time staging ----
  for (int idx = tid; idx < 64 * 256; idx += 256) {
    int s = idx >> 8, jp = idx & 255;
    float2 u = *(const float2*)&ws[UAK_OFF + ((size_t)(b * 64 + s)) * 512 + 2 * jp];
    sUA[s][jp] = pack_h2(u.x, u.y);
  }
  for (int idx = tid; idx < 192 * 32; idx += 256) {
    int row = idx >> 5, sp = idx & 31;
    int col = (row >> 6) * 512 + j0 + (row & 63);
    sKW[row][sp] = KWT32[((size_t)b * G3 + col) * 32 + sp];
  }
  sVa[tid] = Va_w[tid];   sVa[tid + 256] = Va_w[tid + 256];
  sWab[tid] = Wa_b[tid];  sWab[tid + 256] = Wa_b[tid + 256];
  if (tid < 192) sBhh[tid] = b_hh[(tid >> 6) * 512 + j0 + (tid & 63)];
  const float va_b = Va_b[0];
  if (tid < 64) shn[tid] = ws[HALL_OFF + (size_t)b * H + j0 + tid];
  if (tid < 32) sHn2[tid] = pack_h2(shn[2 * tid], shn[2 * tid + 1]);  // wave-0 in-order
  __syncthreads();
  // ---- prologue: publish qp(0) from own h0 slice ----
  {
    const unsigned* wp = WA2T + (size_t)(cb * 32) * 512;
    float a = 0.f, c = 0.f;
#pragma unroll 8
    for (int kk = 0; kk < 32; kk++) {
      unsigned hp = sHn2[kk];
      a = dot2acc(wp[(size_t)kk * 512 + tid], hp, a);
      c = dot2acc(wp[(size_t)kk * 512 + tid + 256], hp, c);
    }
    float* qd = QP + ((size_t)b * 8 + cb) * 512;      // parity 0
    store_coh_f32(qd + tid, a);
    store_coh_f32(qd + tid + 256, c);
  }
  asm volatile("s_waitcnt vmcnt(0)" ::: "memory");
  __syncthreads();
  if (tid == 0) store_coh_i32(&flg[((size_t)b) * 8 + cb], 1);  // flag[t=0]

  for (int t = 0; t < T; ++t) {
    const float* hcur = ws + HALL_OFF + (size_t)t * B * H + b * H;
    // GIE prefetch (independent of exchange)
    float gival = 0.f;
    if (tid < 192)
      gival = GIE[((size_t)b * T + t) * G3 + (tid >> 6) * 512 + j0 + (tid & 63)];
    // ---- wait for the single per-step exchange ----
    if (tid == 0) {
      const int* f = flg + ((size_t)t * B + b) * 8;
      while (!poll8(f)) {}
    }
    __syncthreads();
    // stage full h as packed f16 pairs
    {
      float2 h2 = *(const float2*)&hcur[2 * tid];
      sH2[tid] = pack_h2(h2.x, h2.y);
    }
    // sum 8 qp slices (batched coherent loads) -> full q
    {
      const float* qb = QP + ((size_t)(t & 1) * B + b) * 8 * 512;
      float va[8], vc[8];
#pragma unroll
      for (int i = 0; i < 8; i++) va[i] = load_coh_f32(qb + i * 512 + tid);
#pragma unroll
      for (int i = 0; i < 8; i++) vc[i] = load_coh_f32(qb + i * 512 + tid + 256);
      asm volatile("s_waitcnt vmcnt(0)" ::: "memory");
      __builtin_amdgcn_sched_barrier(0);
      float a0 = ((va[0] + va[1]) + (va[2] + va[3])) + ((va[4] + va[5]) + (va[6] + va[7]));
      float a1 = ((vc[0] + vc[1]) + (vc[2] + vc[3])) + ((vc[4] + vc[5]) + (vc[6] + vc[7]));
      sq[tid] = a0 + sWab[tid];
      sq[tid + 256] = a1 + sWab[tid + 256];
    }
    __syncthreads();
    // ---- gh (global k-major f16; 3 waves) ----
    float gh = 0.f;
    if (tid < 192) {
      int gate = tid >> 6, lane = tid & 63;
      const unsigned* wp = WHH2T + gate * 512 + j0 + lane;
      float g0 = 0.f, g1 = 0.f;
#pragma unroll 8
      for (int kk = 0; kk < 256; kk += 2) {
        g0 = dot2acc(wp[(size_t)kk * 1536], sH2[kk], g0);
        g1 = dot2acc(wp[(size_t)(kk + 1) * 1536], sH2[kk + 1], g1);
      }
      gh = g0 + g1 + sBhh[tid];
    }
    // ---- full scores, all j (s = tid&63 one per lane -> 2-way LDS, free) ----
    {
      int s = tid & 63, jr = tid >> 6;
      const unsigned* ur = &sUA[s][jr * 64];
      const float* qq = sq + jr * 128;
      const float* vv = sVa + jr * 128;
      float a0 = 0.f, a1 = 0.f;
#pragma unroll 4
      for (int i = 0; i < 64; i++) {
        unsigned u = ur[i];
        __half2 hu = *(__half2*)&u;
        a0 += vv[2 * i] * fast_tanh(qq[2 * i] + __low2float(hu));
        a1 += vv[2 * i + 1] * fast_tanh(qq[2 * i + 1] + __high2float(hu));
      }
      spp[s][jr] = a0 + a1;
    }
    __syncthreads();
    // ---- local softmax (wave 0) ----
    if (tid < 64) {
      float v = spp[tid][0] + spp[tid][1] + spp[tid][2] + spp[tid][3] + va_b;
      float m = v;
      for (int o = 32; o; o >>= 1) m = fmaxf(m, __shfl_xor(m, o, 64));
      float e = __expf(v - m);
      float su = e;
      for (int o = 32; o; o >>= 1) su += __shfl_xor(su, o, 64);
      float wt = e / su;
      swt[tid] = wt;
      if (cb == 0) attn_out[((size_t)b * T + t) * S + tid] = wt;
      float w0 = __shfl(wt, 2 * (tid & 31), 64);
      float w1 = __shfl(wt, 2 * (tid & 31) + 1, 64);
      if (tid < 32) sW2[tid] = pack_h2(w0, w1);
    }
    __syncthreads();
    // ---- gic = KWT(f16 LDS) . wt ; combine ----
    if (tid < 192) {
      int gate = tid >> 6, lane = tid & 63;
      float c0 = 0.f, c1 = 0.f;
#pragma unroll 8
      for (int sp = 0; sp < 32; sp += 2) {
        c0 = dot2acc(sKW[tid][sp], sW2[sp], c0);
        c1 = dot2acc(sKW[tid][sp + 1], sW2[sp + 1], c1);
      }
      float gi = gival + c0 + c1;
      if (gate == 0) sga[0][lane] = gi + gh;
      else if (gate == 1) sga[1][lane] = gi + gh;
      else { sga[2][lane] = gi; sga[3][lane] = gh; }
    }
    __syncthreads();
    // ---- GRU update (wave 0) ----
    if (tid < 64) {
      float r = fast_sig(sga[0][tid]);
      float z = fast_sig(sga[1][tid]);
      float n = fast_tanh(sga[2][tid] + r * sga[3][tid]);
      float hold = hcur[j0 + tid];
      float hn = (1.f - z) * n + z * hold;
      HBF[((size_t)b * T + t) * H + j0 + tid] = __float2bfloat16(hn);
      shn[tid] = hn;
      if (t < T - 1)
        store_coh_f32(ws + HALL_OFF + (size_t)(t + 1) * B * H + b * H + j0 + tid, hn);
      else
        ht_out[b * H + j0 + tid] = hn;
    }
    if (tid < 32) sHn2[tid] = pack_h2(shn[2 * tid], shn[2 * tid + 1]);  // same wave, in-order
    __syncthreads();
    // ---- qp(t+1) from own new slice; publish under one flag ----
    if (t < T - 1) {
      const unsigned* wp = WA2T + (size_t)(cb * 32) * 512;
      float a = 0.f, c = 0.f;
#pragma unroll 8
      for (int kk = 0; kk < 32; kk++) {
        unsigned hp = sHn2[kk];
        a = dot2acc(wp[(size_t)kk * 512 + tid], hp, a);
        c = dot2acc(wp[(size_t)kk * 512 + tid + 256], hp, c);
      }
      float* qd = QP + (((size_t)((t + 1) & 1) * B + b) * 8 + cb) * 512;
      store_coh_f32(qd + tid, a);
      store_coh_f32(qd + tid + 256, c);
    }
    asm volatile("s_waitcnt vmcnt(0)" ::: "memory");
    __syncthreads();
    if (tid == 0 && t < T - 1)
      store_coh_i32(&flg[((size_t)(t + 1) * B + b) * 8 + cb], 1);
  }
}

// -------- bf16 MFMA out-projection, XCD-sliced bn, fused softmax stats --------
__global__ __launch_bounds__(256) void k_outgemm(
    const __hip_bfloat16* __restrict__ Abf, const __hip_bfloat16* __restrict__ Bbf,
    const float* __restrict__ bias, float* __restrict__ Cmat,
    float* __restrict__ stats) {
  __shared__ __align__(16) short As[128 * 32];
  __shared__ __align__(16) short Bs[128 * 32];
  __shared__ float sredM[2][128];
  __shared__ float sredS[2][128];
  int xv = blockIdx.x;
  int bn = (xv & 7) * 32 + (xv >> 3);
  if (bn >= 250) return;
  int bm = blockIdx.y;
  int tid = threadIdx.x;
  int lane = tid & 63, wv = tid >> 6;
  int wm = wv >> 1, wn = wv & 1;
  int kc = lane >> 4, rl = lane & 15;
  f32x4 acc[4][4] = {};
  int c0 = wv * 128 + lane, c1 = c0 + 64;
  const __hip_bfloat16* ga0 = Abf + (size_t)(bm * 128 + (c0 >> 2)) * 512 + (c0 & 3) * 8;
  const __hip_bfloat16* ga1 = Abf + (size_t)(bm * 128 + (c1 >> 2)) * 512 + (c1 & 3) * 8;
  const __hip_bfloat16* gb0 = Bbf + (size_t)(bn * 128 + (c0 >> 2)) * 512 + (c0 & 3) * 8;
  const __hip_bfloat16* gb1 = Bbf + (size_t)(bn * 128 + (c1 >> 2)) * 512 + (c1 & 3) * 8;
  for (int k0 = 0; k0 < 512; k0 += 32) {
    __syncthreads();
    __builtin_amdgcn_global_load_lds(
        (const __attribute__((address_space(1))) void*)(ga0 + k0),
        (__attribute__((address_space(3))) void*)((char*)As + wv * 2048), 16, 0, 0);
    __builtin_amdgcn_global_load_lds(
        (const __attribute__((address_space(1))) void*)(ga1 + k0),
        (__attribute__((address_space(3))) void*)((char*)As + wv * 2048 + 1024), 16, 0, 0);
    __builtin_amdgcn_global_load_lds(
        (const __attribute__((address_space(1))) void*)(gb0 + k0),
        (__attribute__((address_space(3))) void*)((char*)Bs + wv * 2048), 16, 0, 0);
    __builtin_amdgcn_global_load_lds(
        (const __attribute__((address_space(1))) void*)(gb1 + k0),
        (__attribute__((address_space(3))) void*)((char*)Bs + wv * 2048 + 1024), 16, 0, 0);
    __syncthreads();
    bf16x8 af[4], bfv[4];
#pragma unroll
    for (int f = 0; f < 4; f++) {
      af[f] = *(const bf16x8*)&As[(wm * 64 + f * 16 + rl) * 32 + kc * 8];
      bfv[f] = *(const bf16x8*)&Bs[(wn * 64 + f * 16 + rl) * 32 + kc * 8];
    }
#pragma unroll
    for (int i = 0; i < 4; i++)
#pragma unroll
      for (int j = 0; j < 4; j++)
        acc[i][j] = __builtin_amdgcn_mfma_f32_16x16x32_bf16(af[i], bfv[j], acc[i][j], 0, 0, 0);
  }
  int cl = lane & 15, rg = lane >> 4;
  float bv[4];
#pragma unroll
  for (int j = 0; j < 4; j++) bv[j] = bias[bn * 128 + wn * 64 + j * 16 + cl];
  float vmax[4][4];
#pragma unroll
  for (int i = 0; i < 4; i++) {
    int m = bm * 128 + wm * 64 + i * 16 + rg * 4;
#pragma unroll
    for (int r = 0; r < 4; r++) vmax[i][r] = -1e30f;
#pragma unroll
    for (int j = 0; j < 4; j++) {
      int n = bn * 128 + wn * 64 + j * 16 + cl;
#pragma unroll
      for (int r = 0; r < 4; r++) {
        float val = acc[i][j][r] + bv[j];
        Cmat[(size_t)(m + r) * V + n] = val;
        vmax[i][r] = fmaxf(vmax[i][r], val);
      }
    }
  }
#pragma unroll
  for (int o = 1; o < 16; o <<= 1)
#pragma unroll
    for (int i = 0; i < 4; i++)
#pragma unroll
      for (int r = 0; r < 4; r++)
        vmax[i][r] = fmaxf(vmax[i][r], __shfl_xor(vmax[i][r], o, 64));
  float vsum[4][4] = {};
#pragma unroll
  for (int i = 0; i < 4; i++)
#pragma unroll
    for (int j = 0; j < 4; j++)
#pragma unroll
      for (int r = 0; r < 4; r++)
        vsum[i][r] += __expf(acc[i][j][r] + bv[j] - vmax[i][r]);
#pragma unroll
  for (int o = 1; o < 16; o <<= 1)
#pragma unroll
    for (int i = 0; i < 4; i++)
#pragma unroll
      for (int r = 0; r < 4; r++)
        vsum[i][r] += __shfl_xor(vsum[i][r], o, 64);
  if (cl == 0) {
#pragma unroll
    for (int i = 0; i < 4; i++)
#pragma unroll
      for (int r = 0; r < 4; r++) {
        int rowl = wm * 64 + i * 16 + rg * 4 + r;
        sredM[wn][rowl] = vmax[i][r];
        sredS[wn][rowl] = vsum[i][r];
      }
  }
  __syncthreads();
  if (tid < 128) {
    float m0 = sredM[0][tid], m1 = sredM[1][tid];
    float M = fmaxf(m0, m1);
    float Sv = sredS[0][tid] * __expf(m0 - M) + sredS[1][tid] * __expf(m1 - M);
    float* st = stats + (size_t)(bm * 128 + tid) * 512 + bn * 2;
    st[0] = M; st[1] = Sv;
  }
}

// -------------------- final pass: lse from stats, subtract in-place --------------------
__global__ __launch_bounds__(256) void k_lsm_final(float* __restrict__ Cmat,
                                                   const float* __restrict__ stats) {
  int row = blockIdx.x;
  int tid = threadIdx.x;
  __shared__ float sM[4], sS[4];
  float m = -1e30f, s = 0.f;
  if (tid < 250) {
    float2 v = *(const float2*)&stats[(size_t)row * 512 + tid * 2];
    m = v.x; s = v.y;
  }
  for (int o = 32; o; o >>= 1) {
    float om = __shfl_xor(m, o, 64), os = __shfl_xor(s, o, 64);
    float nm = fmaxf(m, om);
    s = s * __expf(m - nm) + os * __expf(om - nm);
    m = nm;
  }
  if ((tid & 63) == 0) { sM[tid >> 6] = m; sS[tid >> 6] = s; }
  __syncthreads();
  float M = fmaxf(fmaxf(sM[0], sM[1]), fmaxf(sM[2], sM[3]));
  float Ssum = sS[0] * __expf(sM[0] - M) + sS[1] * __expf(sM[1] - M)
             + sS[2] * __expf(sM[2] - M) + sS[3] * __expf(sM[3] - M);
  float lse = M + __logf(Ssum);
  float* p = Cmat + (size_t)row * V;
  for (int i = tid * 4; i < V; i += 1024) {
    float4 v = *(const float4*)&p[i];
    v.x -= lse; v.y -= lse; v.z -= lse; v.w -= lse;
    *(float4*)&p[i] = v;
  }
}

extern "C" void kernel_launch(void* const* d_in, const int* in_sizes, int n_in,
                              void* d_out, int out_size, void* d_ws, size_t ws_size,
                              hipStream_t stream) {
  (void)in_sizes; (void)n_in; (void)out_size; (void)ws_size;
  const float* keys = (const float*)d_in[0];
  const float* ehid = (const float*)d_in[1];
  const int* tgt    = (const int*)d_in[2];
  const float* emb  = (const float*)d_in[4];
  const float* Wa_w = (const float*)d_in[5];
  const float* Wa_b = (const float*)d_in[6];
  const float* Ua_w = (const float*)d_in[7];
  const float* Ua_b = (const float*)d_in[8];
  const float* Va_w = (const float*)d_in[9];
  const float* Va_b = (const float*)d_in[10];
  const float* W_ih = (const float*)d_in[11];
  const float* W_hh = (const float*)d_in[12];
  const float* b_ih = (const float*)d_in[13];
  const float* b_hh = (const float*)d_in[14];
  const float* out_w = (const float*)d_in[15];
  const float* out_b = (const float*)d_in[16];
  float* ws = (float*)d_ws;
  float* out = (float*)d_out;
  float* logits = out;                              // [B,T,V]
  float* ht_out = out + (size_t)B * T * V;          // [1,B,H]
  float* attn_out = ht_out + (size_t)B * H;         // [B,T,S]

  // consolidated prep (init + f16 convs + packs)
  hipLaunchKernelGGL(k_prep, dim3(6144), dim3(256), 0, stream,
                     ehid, tgt, keys, emb, Ua_w, W_ih, Wa_w, W_hh, ws);
  // UAK = keys @ Ua_w.T + Ua_b  (f16 MFMA)
  hipLaunchKernelGGL(k_mfma128, dim3(4, 16), dim3(256), 0, stream,
                     (const ushort*)(ws + KEYSH_OFF), (const ushort*)(ws + UAWH_OFF),
                     Ua_b, ws + UAK_OFF, 512);
  // GIE = emb[tokens] @ W_ih_lo.T + b_ih  (f16 MFMA)
  hipLaunchKernelGGL(k_mfma128, dim3(12, 16), dim3(256), 0, stream,
                     (const ushort*)(ws + GEH_OFF), (const ushort*)(ws + WLOH_OFF),
                     b_ih, ws + GIE_OFF, G3);
  // KWT (f16 out) = W_ih_ctx @ keys_b^T  (f16 MFMA, per b)
  hipLaunchKernelGGL(k_mfma_kwt, dim3(12, 32), dim3(256), 0, stream,
                     (const ushort*)(ws + WCTXH_OFF), (const ushort*)(ws + KEYSH_OFF),
                     (ushort*)(ws + KWTH_OFF));
  // persistent recurrence (ONE exchange/step; writes ht_out at final step)
  hipLaunchKernelGGL(k_recur, dim3(256), dim3(256), 0, stream,
                     Wa_b, Va_w, Va_b, b_hh,
                     (const unsigned*)(ws + WA2T_OFF), (const unsigned*)(ws + WHH2T_OFF),
                     ws, attn_out, ht_out);
  // bf16 out_w copy into the (now dead) precompute region
  hipLaunchKernelGGL(k_conv_outw, dim3((V * H / 4 + 255) / 256), dim3(256), 0, stream,
                     out_w, (ushort*)(ws + OWBF_OFF), V * H / 4);
  hipLaunchKernelGGL(k_outgemm, dim3(256, 16), dim3(256), 0, stream,
                     (const __hip_bfloat16*)(ws + HBF_OFF),
                     (const __hip_bfloat16*)(ws + OWBF_OFF), out_b, logits,
                     ws + STATS_OFF);
  hipLaunchKernelGGL(k_lsm_final, dim3(BT), dim3(256), 0, stream,
                     logits, ws + STATS_OFF);
}

// Round 16
// 938.041 us; speedup vs baseline: 1.3374x; 1.3374x over previous
//
#include <hip/hip_runtime.h>
#include <hip/hip_bf16.h>
#include <hip/hip_fp16.h>
#include <math.h>

constexpr int B = 32, S = 64, T = 64, H = 512, V = 32000;
constexpr int G3 = 3 * H;     // 1536
constexpr int BT = B * T;     // 2048

// ---- workspace layout (float slots) ----
constexpr size_t UAK_OFF    = 0;          // f32 [B*S][512]      1,048,576
constexpr size_t GIE_OFF    = 1048576;    // f32 [B*T][1536]     -> 4,194,304
constexpr size_t KWTH_OFF   = 4194304;    // f16 [B][G3][64]     -> 5,767,168
constexpr size_t WA2T_OFF   = 5767168;    // u32 [256][512]      -> 5,898,240
constexpr size_t WHH2T_OFF  = 5898240;    // u32 [256][1536]     -> 6,291,456
constexpr size_t SCPT_OFF   = 6291456;    // f32 [T][B][8][64]   -> 7,340,032
constexpr size_t FLG_OFF    = 7340032;    // int [T][B][32]: [0..7]=hS [8..15]=sS
                                          // [16..23]=hF [24..31]=sF -> 7,405,568
constexpr size_t OWBF_OFF   = 0;          // bf16 [V*H] = 8,192,000 slots; aliases all
                                          // of the above (dead after k_recur)
constexpr size_t HALL_OFF   = 8192000;    // f32 [(T+1)*B*H]     -> 9,256,960
constexpr size_t STATS_OFF  = 8192000;    // f32 [2048][512]; reuses HALL (dead after recur)
constexpr size_t HBF_OFF    = 9256960;    // bf16 [B*T*H] -> 9,781,248
// f16 staging for precompute MFMA (dead after precompute)
constexpr size_t KEYSH_OFF  = 10000000;   // f16 [2048][512] -> 10,524,288
constexpr size_t GEH_OFF    = 10524288;   // f16 [2048][512] -> 11,048,576
constexpr size_t UAWH_OFF   = 11048576;   // f16 [512][512]  -> 11,179,648
constexpr size_t WLOH_OFF   = 11179648;   // f16 [1536][512] -> 11,572,864
constexpr size_t WCTXH_OFF  = 11572864;   // f16 [1536][512] -> 11,966,080

typedef __attribute__((ext_vector_type(8))) short bf16x8;
typedef __attribute__((ext_vector_type(4))) float f32x4;
typedef __attribute__((ext_vector_type(4))) int i32x4;
typedef _Float16 f16x8 __attribute__((ext_vector_type(8)));
typedef _Float16 h2v __attribute__((ext_vector_type(2)));

__device__ __forceinline__ float fast_tanh(float x) {
  float ax = fabsf(x);
  float e = __expf(-2.f * ax);
  float r = (1.f - e) / (1.f + e);
  return x < 0.f ? -r : r;
}
__device__ __forceinline__ float fast_sig(float x) {
  return 1.f / (1.f + __expf(-x));
}
__device__ __forceinline__ unsigned pack_h2(float a, float b) {
  __half2 h = __floats2half2_rn(a, b);
  return *(unsigned*)&h;
}
__device__ __forceinline__ ushort f2h(float v) {
  __half h = __float2half(v);
  return *(ushort*)&h;
}
__device__ __forceinline__ void unp2(unsigned v, float* d) {
  __half2 h = *(__half2*)&v;
  d[0] = __low2float(h); d[1] = __high2float(h);
}
__device__ __forceinline__ float dot2acc(unsigned w, unsigned h, float c) {
  return __builtin_amdgcn_fdot2(__builtin_bit_cast(h2v, w),
                                __builtin_bit_cast(h2v, h), c, false);
}
// slow poll: coherence-point (LLC) — always correct
__device__ __forceinline__ int poll8_coh(const int* p) {
  i32x4 a, b;
  asm volatile("global_load_dwordx4 %0, %2, off sc0 sc1\n\t"
               "global_load_dwordx4 %1, %3, off sc0 sc1\n\t"
               "s_waitcnt vmcnt(0)"
               : "=v"(a), "=v"(b) : "v"(p), "v"(p + 4) : "memory");
  return a.x & a.y & a.z & a.w & b.x & b.y & b.z & b.w;
}
// fast poll: bypass L1, read (shared) L2 — fires when producer co-located
__device__ __forceinline__ int poll8_l2(const int* p) {
  i32x4 a, b;
  asm volatile("global_load_dwordx4 %0, %2, off sc0\n\t"
               "global_load_dwordx4 %1, %3, off sc0\n\t"
               "s_waitcnt vmcnt(0)"
               : "=v"(a), "=v"(b) : "v"(p), "v"(p + 4) : "memory");
  return a.x & a.y & a.z & a.w & b.x & b.y & b.z & b.w;
}
__device__ __forceinline__ void store_coh_i32(int* p, int v) {
  asm volatile("global_store_dword %0, %1, off sc0 sc1" :: "v"(p), "v"(v) : "memory");
}
__device__ __forceinline__ void store_plain_i32(int* p, int v) {
  asm volatile("global_store_dword %0, %1, off" :: "v"(p), "v"(v) : "memory");
}
__device__ __forceinline__ void store_coh_f32(float* p, float v) {
  asm volatile("global_store_dword %0, %1, off sc0 sc1" :: "v"(p), "v"(v) : "memory");
}

// -------------------- consolidated prep: init + f16 convs + k-major packs --------------------
__global__ void k_prep(const float* __restrict__ eh, const int* __restrict__ tgt,
                       const float* __restrict__ keys, const float* __restrict__ emb,
                       const float* __restrict__ Ua_w, const float* __restrict__ W_ih,
                       const float* __restrict__ Wa_w, const float* __restrict__ W_hh,
                       float* __restrict__ ws) {
  int blk = blockIdx.x, tid = threadIdx.x;
  if (blk < 256) {
    int i = blk * 256 + tid;
    ((int*)(ws + FLG_OFF))[i] = 0;                 // 65536 flags
    if (i < B * H) ws[HALL_OFF + i] = eh[i];
    return;
  }
  if (blk < 1280) {  // keys -> KEYSH f16
    int i4 = ((blk - 256) * 256 + tid) * 4;
    float4 v = *(const float4*)&keys[i4];
    ushort4 o; o.x = f2h(v.x); o.y = f2h(v.y); o.z = f2h(v.z); o.w = f2h(v.w);
    *(ushort4*)&((ushort*)(ws + KEYSH_OFF))[i4] = o;
    return;
  }
  if (blk < 2304) {  // emb[token(row)] -> GEH f16
    int i4 = ((blk - 1280) * 256 + tid) * 4;
    int row = i4 >> 9, k = i4 & 511;
    int tok = (row & 63) ? tgt[row - 1] : 0;
    float4 v = *(const float4*)&emb[(size_t)tok * 512 + k];
    ushort4 o; o.x = f2h(v.x); o.y = f2h(v.y); o.z = f2h(v.z); o.w = f2h(v.w);
    *(ushort4*)&((ushort*)(ws + GEH_OFF))[i4] = o;
    return;
  }
  if (blk < 2560) {  // Ua_w -> UAWH
    int i4 = ((blk - 2304) * 256 + tid) * 4;
    float4 v = *(const float4*)&Ua_w[i4];
    ushort4 o; o.x = f2h(v.x); o.y = f2h(v.y); o.z = f2h(v.z); o.w = f2h(v.w);
    *(ushort4*)&((ushort*)(ws + UAWH_OFF))[i4] = o;
    return;
  }
  if (blk < 3328) {  // W_ih[:, 0:512] -> WLOH
    int i4 = ((blk - 2560) * 256 + tid) * 4;
    int row = i4 >> 9, k = i4 & 511;
    float4 v = *(const float4*)&W_ih[(size_t)row * 1024 + k];
    ushort4 o; o.x = f2h(v.x); o.y = f2h(v.y); o.z = f2h(v.z); o.w = f2h(v.w);
    *(ushort4*)&((ushort*)(ws + WLOH_OFF))[i4] = o;
    return;
  }
  if (blk < 4096) {  // W_ih[:, 512:1024] -> WCTXH
    int i4 = ((blk - 3328) * 256 + tid) * 4;
    int row = i4 >> 9, k = i4 & 511;
    float4 v = *(const float4*)&W_ih[(size_t)row * 1024 + 512 + k];
    ushort4 o; o.x = f2h(v.x); o.y = f2h(v.y); o.z = f2h(v.z); o.w = f2h(v.w);
    *(ushort4*)&((ushort*)(ws + WCTXH_OFF))[i4] = o;
    return;
  }
  if (blk < 4608) {  // pack Wa k-major [256][512]
    int i = (blk - 4096) * 256 + tid;
    int r = i >> 8, kk = i & 255;
    float2 v = *(const float2*)&Wa_w[(size_t)r * 512 + 2 * kk];
    ((unsigned*)(ws + WA2T_OFF))[(size_t)kk * 512 + r] = pack_h2(v.x, v.y);
    return;
  }
  {                  // pack Whh k-major [256][1536]
    int i = (blk - 4608) * 256 + tid;
    int r = i >> 8, kk = i & 255;
    float2 v = *(const float2*)&W_hh[(size_t)r * 512 + 2 * kk];
    ((unsigned*)(ws + WHH2T_OFF))[(size_t)kk * 1536 + r] = pack_h2(v.x, v.y);
  }
}

// -------------------- out_w fp32 -> bf16 (runs AFTER recurrence; aliases ws) ----
__global__ void k_conv_outw(const float* __restrict__ w, ushort* __restrict__ o, int n4) {
  int i = blockIdx.x * blockDim.x + threadIdx.x;
  if (i < n4) {
    float4 v = *(const float4*)&w[(size_t)i * 4];
    ushort4 u;
    __hip_bfloat16 h0 = __float2bfloat16(v.x); u.x = *(ushort*)&h0;
    __hip_bfloat16 h1 = __float2bfloat16(v.y); u.y = *(ushort*)&h1;
    __hip_bfloat16 h2 = __float2bfloat16(v.z); u.z = *(ushort*)&h2;
    __hip_bfloat16 h3 = __float2bfloat16(v.w); u.w = *(ushort*)&h3;
    *(ushort4*)&o[(size_t)i * 4] = u;
  }
}

// -------- f16 MFMA GEMM 128x128 tiles: C[m*ldc+n] = Ah[m,:].Bh[n,:] + bias[n] --------
__global__ __launch_bounds__(256) void k_mfma128(
    const ushort* __restrict__ Ah, const ushort* __restrict__ Bh,
    const float* __restrict__ bias, float* __restrict__ C, int ldc) {
  __shared__ __align__(16) ushort As[128 * 32];
  __shared__ __align__(16) ushort Bs[128 * 32];
  int bm = blockIdx.y, bn = blockIdx.x;
  int tid = threadIdx.x;
  int lane = tid & 63, wv = tid >> 6;
  int wm = wv >> 1, wn = wv & 1;
  int kc = lane >> 4, rl = lane & 15;
  f32x4 acc[4][4] = {};
  int c0 = wv * 128 + lane, c1 = c0 + 64;
  const ushort* ga0 = Ah + (size_t)(bm * 128 + (c0 >> 2)) * 512 + (c0 & 3) * 8;
  const ushort* ga1 = Ah + (size_t)(bm * 128 + (c1 >> 2)) * 512 + (c1 & 3) * 8;
  const ushort* gb0 = Bh + (size_t)(bn * 128 + (c0 >> 2)) * 512 + (c0 & 3) * 8;
  const ushort* gb1 = Bh + (size_t)(bn * 128 + (c1 >> 2)) * 512 + (c1 & 3) * 8;
  for (int k0 = 0; k0 < 512; k0 += 32) {
    __syncthreads();
    __builtin_amdgcn_global_load_lds(
        (const __attribute__((address_space(1))) void*)(ga0 + k0),
        (__attribute__((address_space(3))) void*)((char*)As + wv * 2048), 16, 0, 0);
    __builtin_amdgcn_global_load_lds(
        (const __attribute__((address_space(1))) void*)(ga1 + k0),
        (__attribute__((address_space(3))) void*)((char*)As + wv * 2048 + 1024), 16, 0, 0);
    __builtin_amdgcn_global_load_lds(
        (const __attribute__((address_space(1))) void*)(gb0 + k0),
        (__attribute__((address_space(3))) void*)((char*)Bs + wv * 2048), 16, 0, 0);
    __builtin_amdgcn_global_load_lds(
        (const __attribute__((address_space(1))) void*)(gb1 + k0),
        (__attribute__((address_space(3))) void*)((char*)Bs + wv * 2048 + 1024), 16, 0, 0);
    __syncthreads();
    f16x8 af[4], bfv[4];
#pragma unroll
    for (int f = 0; f < 4; f++) {
      af[f] = *(const f16x8*)&As[(wm * 64 + f * 16 + rl) * 32 + kc * 8];
      bfv[f] = *(const f16x8*)&Bs[(wn * 64 + f * 16 + rl) * 32 + kc * 8];
    }
#pragma unroll
    for (int i = 0; i < 4; i++)
#pragma unroll
      for (int j = 0; j < 4; j++)
        acc[i][j] = __builtin_amdgcn_mfma_f32_16x16x32_f16(af[i], bfv[j], acc[i][j], 0, 0, 0);
  }
  int cl = lane & 15, rg = lane >> 4;
#pragma unroll
  for (int i = 0; i < 4; i++) {
    int m = bm * 128 + wm * 64 + i * 16 + rg * 4;
#pragma unroll
    for (int j = 0; j < 4; j++) {
      int n = bn * 128 + wn * 64 + j * 16 + cl;
      float bv = bias[n];
#pragma unroll
      for (int r = 0; r < 4; r++)
        C[(size_t)(m + r) * ldc + n] = acc[i][j][r] + bv;
    }
  }
}

// -------- f16 MFMA KWT: per b, [1536 x 64] = Wctx[1536,512] . keys_b[64,512]^T -> f16 --------
__global__ __launch_bounds__(256) void k_mfma_kwt(
    const ushort* __restrict__ Wctxh, const ushort* __restrict__ keysh,
    ushort* __restrict__ KWTh) {
  __shared__ __align__(16) ushort As[128 * 32];
  __shared__ __align__(16) ushort Bs[64 * 32];
  int bm = blockIdx.x, b = blockIdx.y;
  int tid = threadIdx.x;
  int lane = tid & 63, wv = tid >> 6;
  int kc = lane >> 4, rl = lane & 15;
  f32x4 acc[2][4] = {};
  int c0 = tid, c2 = tid + 256;
  const ushort* ga0 = Wctxh + (size_t)(bm * 128 + (c0 >> 2)) * 512 + (c0 & 3) * 8;
  const ushort* ga1 = Wctxh + (size_t)(bm * 128 + (c2 >> 2)) * 512 + (c2 & 3) * 8;
  const ushort* gb0 = keysh + (size_t)(b * 64 + (c0 >> 2)) * 512 + (c0 & 3) * 8;
  for (int k0 = 0; k0 < 512; k0 += 32) {
    __syncthreads();
    __builtin_amdgcn_global_load_lds(
        (const __attribute__((address_space(1))) void*)(ga0 + k0),
        (__attribute__((address_space(3))) void*)((char*)As + wv * 1024), 16, 0, 0);
    __builtin_amdgcn_global_load_lds(
        (const __attribute__((address_space(1))) void*)(ga1 + k0),
        (__attribute__((address_space(3))) void*)((char*)As + 4096 + wv * 1024), 16, 0, 0);
    __builtin_amdgcn_global_load_lds(
        (const __attribute__((address_space(1))) void*)(gb0 + k0),
        (__attribute__((address_space(3))) void*)((char*)Bs + wv * 1024), 16, 0, 0);
    __syncthreads();
    f16x8 af[2], bfv[4];
#pragma unroll
    for (int f = 0; f < 2; f++)
      af[f] = *(const f16x8*)&As[(wv * 32 + f * 16 + rl) * 32 + kc * 8];
#pragma unroll
    for (int j = 0; j < 4; j++)
      bfv[j] = *(const f16x8*)&Bs[(j * 16 + rl) * 32 + kc * 8];
#pragma unroll
    for (int i = 0; i < 2; i++)
#pragma unroll
      for (int j = 0; j < 4; j++)
        acc[i][j] = __builtin_amdgcn_mfma_f32_16x16x32_f16(af[i], bfv[j], acc[i][j], 0, 0, 0);
  }
  int cl = lane & 15, rg = lane >> 4;
#pragma unroll
  for (int i = 0; i < 2; i++) {
    int m = bm * 128 + wv * 32 + i * 16 + rg * 4;
#pragma unroll
    for (int j = 0; j < 4; j++) {
      int n = j * 16 + cl;
#pragma unroll
      for (int r = 0; r < 4; r++)
        KWTh[((size_t)b * G3 + m + r) * 64 + n] = f2h(acc[i][j][r]);
    }
  }
}

// -------------------- persistent recurrence (dual-flag fast/slow handshakes) ----------
__global__ __launch_bounds__(256) void k_recur(
    const float* __restrict__ Wa_b, const float* __restrict__ Va_w,
    const float* __restrict__ Va_b, const float* __restrict__ b_hh,
    const unsigned* __restrict__ WA2T, const unsigned* __restrict__ WHH2T,
    float* __restrict__ ws, float* __restrict__ attn_out, float* __restrict__ ht_out) {
  const int w = blockIdx.x;
  const int tid = threadIdx.x;
  const int b = w & 31, cb = w >> 5;
  const int j0 = cb * 64;
  int* flg = (int*)(ws + FLG_OFF);
  __hip_bfloat16* HBF = (__hip_bfloat16*)(ws + HBF_OFF);
  const float* GIE = ws + GIE_OFF;
  float* SCPT = ws + SCPT_OFF;
  const ushort* KWTh = (const ushort*)(ws + KWTH_OFF);

  __shared__ float sKWT[192][68];   // 52.2 KB
  __shared__ float sUAK[64][68];    // 17.4 KB
  __shared__ unsigned sH2[256];
  __shared__ float sq[64];
  __shared__ float qp[64][5];
  __shared__ float spp[64][5];
  __shared__ float swt[64];
  __shared__ float sga[4][64];
  __shared__ float sVa[64], sWab[64], sBhh[192];

  // ---- one-time staging ----
#pragma unroll
  for (int g = 0; g < 3; g++) {
    int jl = tid >> 2, part = tid & 3;
    const ushort* src = KWTh + ((size_t)b * G3 + g * 512 + j0 + jl) * 64 + part * 16;
    float* dst = &sKWT[g * 64 + jl][part * 16];
    uint4 u0 = *(const uint4*)src;
    uint4 u1 = *(const uint4*)(src + 8);
    unp2(u0.x, dst); unp2(u0.y, dst + 2); unp2(u0.z, dst + 4); unp2(u0.w, dst + 6);
    unp2(u1.x, dst + 8); unp2(u1.y, dst + 10); unp2(u1.z, dst + 12); unp2(u1.w, dst + 14);
  }
  {
    int s = tid >> 2, part = tid & 3;
    const float* src = ws + UAK_OFF + ((size_t)(b * 64 + s)) * 512 + j0 + part * 16;
    float* dst = &sUAK[s][part * 16];
#pragma unroll
    for (int i = 0; i < 16; i += 4) *(float4*)&dst[i] = *(const float4*)&src[i];
  }
  if (tid < 64) { sVa[tid] = Va_w[j0 + tid]; sWab[tid] = Wa_b[j0 + tid]; }
  if (tid < 192) sBhh[tid] = b_hh[(tid >> 6) * 512 + j0 + (tid & 63)];
  const float va_b = Va_b[0];
  __syncthreads();

  for (int t = 0; t < T; ++t) {
    const float* hcur = ws + HALL_OFF + (size_t)t * B * H + b * H;
    // GIE prefetch (independent of h) issues before the wait
    float gival = 0.f;
    if (tid < 192)
      gival = GIE[((size_t)b * T + t) * G3 + (tid >> 6) * 512 + j0 + (tid & 63)];
    // ---- wait for h_t (dual-flag) ----
    if (t > 0) {
      if (tid == 0) {
        const int* fF = flg + (size_t)(t - 1) * 1024 + b * 32 + 16;
        const int* fS = flg + (size_t)(t - 1) * 1024 + b * 32;
        while (true) {
          if (poll8_l2(fF)) break;
          if (poll8_coh(fS)) break;
        }
      }
    }
    __syncthreads();
    // stage h as packed f16 pairs (float2 per thread, coalesced)
    {
      float2 h2 = *(const float2*)&hcur[2 * tid];
      sH2[tid] = pack_h2(h2.x, h2.y);
    }
    __syncthreads();

    // ---- q slice (coalesced k-major f16) ----
    {
      int jq = tid & 63, kp = tid >> 6;
      const unsigned* wp = WA2T + (size_t)(kp * 64) * 512 + j0 + jq;
      float acc = 0.f;
#pragma unroll 8
      for (int kk = 0; kk < 64; kk++)
        acc = dot2acc(wp[(size_t)kk * 512], sH2[kp * 64 + kk], acc);
      qp[jq][kp] = acc;
    }
    __syncthreads();
    if (tid < 64)
      sq[tid] = qp[tid][0] + qp[tid][1] + qp[tid][2] + qp[tid][3] + sWab[tid];
    __syncthreads();
    // ---- score partials over this WG's 64-j slice ----
    {
      int s = tid >> 2, jc = tid & 3;
      float accs = 0.f;
#pragma unroll
      for (int i = 0; i < 16; i++) {
        int j = jc * 16 + i;
        accs += sVa[j] * fast_tanh(sq[j] + sUAK[s][j]);
      }
      spp[s][jc] = accs;
    }
    __syncthreads();
    if (tid < 64) {
      float v = spp[tid][0] + spp[tid][1] + spp[tid][2] + spp[tid][3];
      if (cb == 0) v += va_b;
      store_coh_f32(SCPT + (((size_t)t * B + b) * 8 + cb) * 64 + tid, v);
    }
    if (tid == 0) {
      asm volatile("s_waitcnt vmcnt(0)" ::: "memory");
      store_plain_i32(flg + (size_t)t * 1024 + b * 32 + 24 + cb, 1);
      store_coh_i32(flg + (size_t)t * 1024 + b * 32 + 8 + cb, 1);
    }

    // ---- gh (coalesced k-major f16), overlaps peers' score phase ----
    float gh = 0.f;
    if (tid < 192) {
      int gate = tid >> 6, lane = tid & 63;
      const unsigned* wp = WHH2T + gate * 512 + j0 + lane;
      float g0 = 0.f, g1 = 0.f;
#pragma unroll 8
      for (int kk = 0; kk < 256; kk += 2) {
        g0 = dot2acc(wp[(size_t)kk * 1536], sH2[kk], g0);
        g1 = dot2acc(wp[(size_t)(kk + 1) * 1536], sH2[kk + 1], g1);
      }
      gh = g0 + g1 + sBhh[tid];
    }
    // ---- wait all 8 score slices of batch b (dual-flag) ----
    if (tid == 0) {
      const int* fF = flg + (size_t)t * 1024 + b * 32 + 24;
      const int* fS = flg + (size_t)t * 1024 + b * 32 + 8;
      while (true) {
        if (poll8_l2(fF)) break;
        if (poll8_coh(fS)) break;
      }
    }
    __syncthreads();
    // ---- direct 8-slice reduce (plain first-touch loads) + softmax ----
    if (tid < 64) {
      const float* sp = SCPT + ((size_t)t * B + b) * 512;
      float v = (sp[tid] + sp[64 + tid]) + (sp[128 + tid] + sp[192 + tid])
              + (sp[256 + tid] + sp[320 + tid]) + (sp[384 + tid] + sp[448 + tid]);
      float m = v;
      for (int o = 32; o; o >>= 1) m = fmaxf(m, __shfl_xor(m, o, 64));
      float e = __expf(v - m);
      float su = e;
      for (int o = 32; o; o >>= 1) su += __shfl_xor(su, o, 64);
      float wt = e / su;
      swt[tid] = wt;
      if (cb == 0) attn_out[((size_t)b * T + t) * S + tid] = wt;
    }
    __syncthreads();
    // ---- gic = KWT . wt (LDS f32) ; combine ----
    if (tid < 192) {
      int gate = tid >> 6, lane = tid & 63;
      float gic = 0.f;
#pragma unroll
      for (int s4 = 0; s4 < 64; s4 += 4) {
        float4 k4 = *(const float4*)&sKWT[tid][s4];
        gic += k4.x * swt[s4] + k4.y * swt[s4 + 1] + k4.z * swt[s4 + 2] + k4.w * swt[s4 + 3];
      }
      float gi = gival + gic;
      if (gate == 0) sga[0][lane] = gi + gh;
      else if (gate == 1) sga[1][lane] = gi + gh;
      else { sga[2][lane] = gi; sga[3][lane] = gh; }
    }
    __syncthreads();
    // ---- GRU update + direct publish ----
    if (tid < 64) {
      float r = fast_sig(sga[0][tid]);
      float z = fast_sig(sga[1][tid]);
      float n = fast_tanh(sga[2][tid] + r * sga[3][tid]);
      float hold = hcur[j0 + tid];
      float hn = (1.f - z) * n + z * hold;
      HBF[((size_t)b * T + t) * H + j0 + tid] = __float2bfloat16(hn);
      if (t < T - 1)
        store_coh_f32(ws + HALL_OFF + (size_t)(t + 1) * B * H + b * H + j0 + tid, hn);
      else
        ht_out[b * H + j0 + tid] = hn;
    }
    if (tid == 0 && t < T - 1) {
      asm volatile("s_waitcnt vmcnt(0)" ::: "memory");
      store_plain_i32(flg + (size_t)t * 1024 + b * 32 + 16 + cb, 1);
      store_coh_i32(flg + (size_t)t * 1024 + b * 32 + cb, 1);
    }
    __syncthreads();   // protect LDS reuse before next iteration
  }
}

// -------- bf16 MFMA out-projection, XCD-sliced bn, fused softmax stats --------
__global__ __launch_bounds__(256) void k_outgemm(
    const __hip_bfloat16* __restrict__ Abf, const __hip_bfloat16* __restrict__ Bbf,
    const float* __restrict__ bias, float* __restrict__ Cmat,
    float* __restrict__ stats) {
  __shared__ __align__(16) short As[128 * 32];
  __shared__ __align__(16) short Bs[128 * 32];
  __shared__ float sredM[2][128];
  __shared__ float sredS[2][128];
  int xv = blockIdx.x;
  int bn = (xv & 7) * 32 + (xv >> 3);
  if (bn >= 250) return;
  int bm = blockIdx.y;
  int tid = threadIdx.x;
  int lane = tid & 63, wv = tid >> 6;
  int wm = wv >> 1, wn = wv & 1;
  int kc = lane >> 4, rl = lane & 15;
  f32x4 acc[4][4] = {};
  int c0 = wv * 128 + lane, c1 = c0 + 64;
  const __hip_bfloat16* ga0 = Abf + (size_t)(bm * 128 + (c0 >> 2)) * 512 + (c0 & 3) * 8;
  const __hip_bfloat16* ga1 = Abf + (size_t)(bm * 128 + (c1 >> 2)) * 512 + (c1 & 3) * 8;
  const __hip_bfloat16* gb0 = Bbf + (size_t)(bn * 128 + (c0 >> 2)) * 512 + (c0 & 3) * 8;
  const __hip_bfloat16* gb1 = Bbf + (size_t)(bn * 128 + (c1 >> 2)) * 512 + (c1 & 3) * 8;
  for (int k0 = 0; k0 < 512; k0 += 32) {
    __syncthreads();
    __builtin_amdgcn_global_load_lds(
        (const __attribute__((address_space(1))) void*)(ga0 + k0),
        (__attribute__((address_space(3))) void*)((char*)As + wv * 2048), 16, 0, 0);
    __builtin_amdgcn_global_load_lds(
        (const __attribute__((address_space(1))) void*)(ga1 + k0),
        (__attribute__((address_space(3))) void*)((char*)As + wv * 2048 + 1024), 16, 0, 0);
    __builtin_amdgcn_global_load_lds(
        (const __attribute__((address_space(1))) void*)(gb0 + k0),
        (__attribute__((address_space(3))) void*)((char*)Bs + wv * 2048), 16, 0, 0);
    __builtin_amdgcn_global_load_lds(
        (const __attribute__((address_space(1))) void*)(gb1 + k0),
        (__attribute__((address_space(3))) void*)((char*)Bs + wv * 2048 + 1024), 16, 0, 0);
    __syncthreads();
    bf16x8 af[4], bfv[4];
#pragma unroll
    for (int f = 0; f < 4; f++) {
      af[f] = *(const bf16x8*)&As[(wm * 64 + f * 16 + rl) * 32 + kc * 8];
      bfv[f] = *(const bf16x8*)&Bs[(wn * 64 + f * 16 + rl) * 32 + kc * 8];
    }
#pragma unroll
    for (int i = 0; i < 4; i++)
#pragma unroll
      for (int j = 0; j < 4; j++)
        acc[i][j] = __builtin_amdgcn_mfma_f32_16x16x32_bf16(af[i], bfv[j], acc[i][j], 0, 0, 0);
  }
  int cl = lane & 15, rg = lane >> 4;
  float bv[4];
#pragma unroll
  for (int j = 0; j < 4; j++) bv[j] = bias[bn * 128 + wn * 64 + j * 16 + cl];
  float vmax[4][4];
#pragma unroll
  for (int i = 0; i < 4; i++) {
    int m = bm * 128 + wm * 64 + i * 16 + rg * 4;
#pragma unroll
    for (int r = 0; r < 4; r++) vmax[i][r] = -1e30f;
#pragma unroll
    for (int j = 0; j < 4; j++) {
      int n = bn * 128 + wn * 64 + j * 16 + cl;
#pragma unroll
      for (int r = 0; r < 4; r++) {
        float val = acc[i][j][r] + bv[j];
        Cmat[(size_t)(m + r) * V + n] = val;
        vmax[i][r] = fmaxf(vmax[i][r], val);
      }
    }
  }
#pragma unroll
  for (int o = 1; o < 16; o <<= 1)
#pragma unroll
    for (int i = 0; i < 4; i++)
#pragma unroll
      for (int r = 0; r < 4; r++)
        vmax[i][r] = fmaxf(vmax[i][r], __shfl_xor(vmax[i][r], o, 64));
  float vsum[4][4] = {};
#pragma unroll
  for (int i = 0; i < 4; i++)
#pragma unroll
    for (int j = 0; j < 4; j++)
#pragma unroll
      for (int r = 0; r < 4; r++)
        vsum[i][r] += __expf(acc[i][j][r] + bv[j] - vmax[i][r]);
#pragma unroll
  for (int o = 1; o < 16; o <<= 1)
#pragma unroll
    for (int i = 0; i < 4; i++)
#pragma unroll
      for (int r = 0; r < 4; r++)
        vsum[i][r] += __shfl_xor(vsum[i][r], o, 64);
  if (cl == 0) {
#pragma unroll
    for (int i = 0; i < 4; i++)
#pragma unroll
      for (int r = 0; r < 4; r++) {
        int rowl = wm * 64 + i * 16 + rg * 4 + r;
        sredM[wn][rowl] = vmax[i][r];
        sredS[wn][rowl] = vsum[i][r];
      }
  }
  __syncthreads();
  if (tid < 128) {
    float m0 = sredM[0][tid], m1 = sredM[1][tid];
    float M = fmaxf(m0, m1);
    float Sv = sredS[0][tid] * __expf(m0 - M) + sredS[1][tid] * __expf(m1 - M);
    float* st = stats + (size_t)(bm * 128 + tid) * 512 + bn * 2;
    st[0] = M; st[1] = Sv;
  }
}

// -------------------- final pass: lse from stats, subtract in-place --------------------
__global__ __launch_bounds__(256) void k_lsm_final(float* __restrict__ Cmat,
                                                   const float* __restrict__ stats) {
  int row = blockIdx.x;
  int tid = threadIdx.x;
  __shared__ float sM[4], sS[4];
  float m = -1e30f, s = 0.f;
  if (tid < 250) {
    float2 v = *(const float2*)&stats[(size_t)row * 512 + tid * 2];
    m = v.x; s = v.y;
  }
  for (int o = 32; o; o >>= 1) {
    float om = __shfl_xor(m, o, 64), os = __shfl_xor(s, o, 64);
    float nm = fmaxf(m, om);
    s = s * __expf(m - nm) + os * __expf(om - nm);
    m = nm;
  }
  if ((tid & 63) == 0) { sM[tid >> 6] = m; sS[tid >> 6] = s; }
  __syncthreads();
  float M = fmaxf(fmaxf(sM[0], sM[1]), fmaxf(sM[2], sM[3]));
  float Ssum = sS[0] * __expf(sM[0] - M) + sS[1] * __expf(sM[1] - M)
             + sS[2] * __expf(sM[2] - M) + sS[3] * __expf(sM[3] - M);
  float lse = M + __logf(Ssum);
  float* p = Cmat + (size_t)row * V;
  for (int i = tid * 4; i < V; i += 1024) {
    float4 v = *(const float4*)&p[i];
    v.x -= lse; v.y -= lse; v.z -= lse; v.w -= lse;
    *(float4*)&p[i] = v;
  }
}

extern "C" void kernel_launch(void* const* d_in, const int* in_sizes, int n_in,
                              void* d_out, int out_size, void* d_ws, size_t ws_size,
                              hipStream_t stream) {
  (void)in_sizes; (void)n_in; (void)out_size; (void)ws_size;
  const float* keys = (const float*)d_in[0];
  const float* ehid = (const float*)d_in[1];
  const int* tgt    = (const int*)d_in[2];
  const float* emb  = (const float*)d_in[4];
  const float* Wa_w = (const float*)d_in[5];
  const float* Wa_b = (const float*)d_in[6];
  const float* Ua_w = (const float*)d_in[7];
  const float* Ua_b = (const float*)d_in[8];
  const float* Va_w = (const float*)d_in[9];
  const float* Va_b = (const float*)d_in[10];
  const float* W_ih = (const float*)d_in[11];
  const float* W_hh = (const float*)d_in[12];
  const float* b_ih = (const float*)d_in[13];
  const float* b_hh = (const float*)d_in[14];
  const float* out_w = (const float*)d_in[15];
  const float* out_b = (const float*)d_in[16];
  float* ws = (float*)d_ws;
  float* out = (float*)d_out;
  float* logits = out;                              // [B,T,V]
  float* ht_out = out + (size_t)B * T * V;          // [1,B,H]
  float* attn_out = ht_out + (size_t)B * H;         // [B,T,S]

  // consolidated prep (init + f16 convs + packs)
  hipLaunchKernelGGL(k_prep, dim3(6144), dim3(256), 0, stream,
                     ehid, tgt, keys, emb, Ua_w, W_ih, Wa_w, W_hh, ws);
  // UAK = keys @ Ua_w.T + Ua_b  (f16 MFMA)
  hipLaunchKernelGGL(k_mfma128, dim3(4, 16), dim3(256), 0, stream,
                     (const ushort*)(ws + KEYSH_OFF), (const ushort*)(ws + UAWH_OFF),
                     Ua_b, ws + UAK_OFF, 512);
  // GIE = emb[tokens] @ W_ih_lo.T + b_ih  (f16 MFMA)
  hipLaunchKernelGGL(k_mfma128, dim3(12, 16), dim3(256), 0, stream,
                     (const ushort*)(ws + GEH_OFF), (const ushort*)(ws + WLOH_OFF),
                     b_ih, ws + GIE_OFF, G3);
  // KWT (f16 out) = W_ih_ctx @ keys_b^T  (f16 MFMA, per b)
  hipLaunchKernelGGL(k_mfma_kwt, dim3(12, 32), dim3(256), 0, stream,
                     (const ushort*)(ws + WCTXH_OFF), (const ushort*)(ws + KEYSH_OFF),
                     (ushort*)(ws + KWTH_OFF));
  // persistent recurrence (writes ht_out at final step)
  hipLaunchKernelGGL(k_recur, dim3(256), dim3(256), 0, stream,
                     Wa_b, Va_w, Va_b, b_hh,
                     (const unsigned*)(ws + WA2T_OFF), (const unsigned*)(ws + WHH2T_OFF),
                     ws, attn_out, ht_out);
  // bf16 out_w copy into the (now dead) precompute region
  hipLaunchKernelGGL(k_conv_outw, dim3((V * H / 4 + 255) / 256), dim3(256), 0, stream,
                     out_w, (ushort*)(ws + OWBF_OFF), V * H / 4);
  hipLaunchKernelGGL(k_outgemm, dim3(256, 16), dim3(256), 0, stream,
                     (const __hip_bfloat16*)(ws + HBF_OFF),
                     (const __hip_bfloat16*)(ws + OWBF_OFF), out_b, logits,
                     ws + STATS_OFF);
  hipLaunchKernelGGL(k_lsm_final, dim3(BT), dim3(256), 0, stream,
                     logits, ws + STATS_OFF);
}